// Round 4
// baseline (629.947 us; speedup 1.0000x reference)
//
#include <hip/hip_runtime.h>
#include <hip/hip_bf16.h>
#include <math.h>

// Problem constants
#define M_ 2048
#define K_ 1024
#define V_ 50000
#define VP_ 50048        // V padded to 128
#define CV_ 120
#define NC_ (V_ + CV_)   // 50120 out row stride
#define S_ 100
#define B_ 32
#define PAD_IDX_ 1

// GEMM tiling
#define BM 128
#define BN 128
#define BK 32
#define NB_ (VP_ / BN)                  // 391 N-blocks
#define NWG_ ((M_ / BM) * NB_)          // 6256
#define WPX_ (NWG_ / 8)                 // 782 (exact)
#define PSTRIDE 800                     // partials row stride (2*NB_=782 used)

typedef float f32x4 __attribute__((ext_vector_type(4)));
typedef __bf16 bf16x8 __attribute__((ext_vector_type(8)));
typedef unsigned short ushort;

__device__ __forceinline__ void async_copy16(const void* g, void* l) {
    __builtin_amdgcn_global_load_lds(
        (const __attribute__((address_space(1))) void*)g,
        (__attribute__((address_space(3))) void*)l, 16, 0, 0);
}
// quarter-wave conflict-free chunk swizzle: physical chunk p holds logical
// chunk p ^ SIG(row); rows 0..15 at fixed logical chunk then cover all 8
// 16B-slots of a 128B line exactly twice (slot = (row&1)*4 | (c^SIG(row))).
#define SIG(row) (((row) >> 1) & 3)

// ---------------------------------------------------------------------------
// fused: hidden->bf16 (plain row-major), copy gate. 1 wave per row.
__global__ __launch_bounds__(256)
void k_prep(const float* __restrict__ hidden, const float* __restrict__ w_copy,
            const float* __restrict__ b_copy, __bf16* __restrict__ Ab,
            float* __restrict__ cvec)
{
    int n = blockIdx.x * 4 + (threadIdx.x >> 6);
    int lane = threadIdx.x & 63;
    const float* h = hidden + (size_t)n * K_;
    __bf16* arow = Ab + (size_t)n * K_;
    float s = 0.f;
#pragma unroll
    for (int g = 0; g < 2; ++g) {
        int gg = 2 * lane + g;            // granule 0..127 (8 elems each)
        f32x4 a = *(const f32x4*)(h + gg * 8);
        f32x4 b = *(const f32x4*)(h + gg * 8 + 4);
        f32x4 wa = *(const f32x4*)(w_copy + gg * 8);
        f32x4 wb = *(const f32x4*)(w_copy + gg * 8 + 4);
        s += a[0]*wa[0] + a[1]*wa[1] + a[2]*wa[2] + a[3]*wa[3]
           + b[0]*wb[0] + b[1]*wb[1] + b[2]*wb[2] + b[3]*wb[3];
        bf16x8 v;
        v[0]=(__bf16)a[0]; v[1]=(__bf16)a[1]; v[2]=(__bf16)a[2]; v[3]=(__bf16)a[3];
        v[4]=(__bf16)b[0]; v[5]=(__bf16)b[1]; v[6]=(__bf16)b[2]; v[7]=(__bf16)b[3];
        *(bf16x8*)(arow + gg * 8) = v;
    }
#pragma unroll
    for (int off = 32; off; off >>= 1) s += __shfl_down(s, off);
    if (lane == 0) cvec[n] = 1.f / (1.f + __expf(-(s + b_copy[0])));
}

// ---------------------------------------------------------------------------
// W [K][V] fp32 -> Wt [VP][K] bf16, transposed; pad rows zeroed
__global__ __launch_bounds__(256)
void k_wt(const float* __restrict__ W, __bf16* __restrict__ Wt)
{
    __shared__ __bf16 t[64][72];
    int v0 = blockIdx.x * 64;
    int k0 = blockIdx.y * 64;
    int tid = threadIdx.x;
    int kr = tid >> 4;          // 0..15
    int vq = tid & 15;
    int v4 = v0 + vq * 4;
#pragma unroll
    for (int i = 0; i < 4; ++i) {
        int k = k0 + kr + i * 16;
        f32x4 val = {};
        if (v4 < V_) val = *(const f32x4*)(W + (size_t)k * V_ + v4);
#pragma unroll
        for (int c = 0; c < 4; ++c) t[vq * 4 + c][kr + i * 16] = (__bf16)val[c];
    }
    __syncthreads();
    int vr = tid >> 2;          // 0..63 local row
    int q  = tid & 3;
    __bf16* dst = Wt + (size_t)(v0 + vr) * K_ + k0;
#pragma unroll
    for (int i = 0; i < 2; ++i) {
        bf16x8 o;
#pragma unroll
        for (int e = 0; e < 8; ++e) o[e] = t[vr][q * 8 + i * 32 + e];
        *(bf16x8*)(dst + q * 8 + i * 32) = o;
    }
}

// ---------------------------------------------------------------------------
// one-hot src_map -> integer ids [S*B]
__global__ __launch_bounds__(256)
void k_ids(const float* __restrict__ src_map, int* __restrict__ ids)
{
    int i = blockIdx.x * 256 + threadIdx.x;
    if (i < S_ * B_) {
        const float* r = src_map + (size_t)i * CV_;
        int id = 0;
        for (int v = 0; v < CV_; ++v)
            if (r[v] > 0.5f) { id = v; break; }
        ids[i] = id;
    }
}

// ---------------------------------------------------------------------------
// GEMM: e = exp(A.Wt^T + b) (PAD col->0); bf16 E store; per-block row partials
template<bool E16>
__global__ __launch_bounds__(256, 4)
void k_gemm_exp(const __bf16* __restrict__ A, const __bf16* __restrict__ Bt,
                const float* __restrict__ bias, float* __restrict__ out,
                ushort* __restrict__ E, float* __restrict__ part)
{
    __shared__ __bf16 lA[2][BM * BK];   // 8 KB per buf
    __shared__ __bf16 lB[2][BN * BK];

    const int tid  = threadIdx.x;
    const int lane = tid & 63;
    const int wid  = tid >> 6;
    const int wm   = wid >> 1;
    const int wn   = wid & 1;

    // bijective XCD swizzle: 6256 = 8 * 782
    int orig = blockIdx.y * (M_ / BM) + blockIdx.x;
    int nid  = (orig & 7) * WPX_ + (orig >> 3);
    const int m0 = (nid & 15) * BM;
    const int nb = nid >> 4;
    const int n0 = nb * BN;

    f32x4 acc[4][4] = {};

#define STAGE(buf, kt)                                                        \
    do {                                                                      \
        _Pragma("unroll")                                                     \
        for (int j = 0; j < 2; ++j) {                                         \
            int g = j * 256 + tid; int row = g >> 2;                          \
            int ch = (g & 3) ^ SIG(row);                                      \
            async_copy16(A + (size_t)(m0 + row) * K_ + (kt) * BK + ch * 8,    \
                         &lA[buf][(j * 256 + wid * 64) * 8]);                 \
        }                                                                     \
        _Pragma("unroll")                                                     \
        for (int j = 0; j < 2; ++j) {                                         \
            int g = j * 256 + tid; int row = g >> 2;                          \
            int ch = (g & 3) ^ SIG(row);                                      \
            async_copy16(Bt + (size_t)(n0 + row) * K_ + (kt) * BK + ch * 8,   \
                         &lB[buf][(j * 256 + wid * 64) * 8]);                 \
        }                                                                     \
    } while (0)

    STAGE(0, 0);
    __syncthreads();

    // fragment row = ...16*x + (lane&15) -> SIG(row) = (lane>>1)&3
    const int chx = (((lane >> 4) ^ ((lane >> 1) & 3))) * 8;
    int cur = 0;
    for (int kt = 0; kt < K_ / BK; ++kt) {
        if (kt < K_ / BK - 1) STAGE(cur ^ 1, kt + 1);
        bf16x8 fa[4], fb[4];
#pragma unroll
        for (int mf = 0; mf < 4; ++mf)
            fa[mf] = *(const bf16x8*)(&lA[cur][(wm * 64 + mf * 16 + (lane & 15)) * BK + chx]);
#pragma unroll
        for (int nf = 0; nf < 4; ++nf)
            fb[nf] = *(const bf16x8*)(&lB[cur][(wn * 64 + nf * 16 + (lane & 15)) * BK + chx]);
#pragma unroll
        for (int mf = 0; mf < 4; ++mf)
#pragma unroll
            for (int nf = 0; nf < 4; ++nf)
                acc[mf][nf] = __builtin_amdgcn_mfma_f32_16x16x32_bf16(
                    fa[mf], fb[nf], acc[mf][nf], 0, 0, 0);
        __syncthreads();   // drains vmcnt(0): next tile staged; LDS reads done
        cur ^= 1;
    }
#undef STAGE

    // epilogue: bias + exp + store + per-block row-sum partials
    const int rbase = m0 + wm * 64;
    const int cbase = n0 + wn * 64;
    float psum[4][4] = {};
#pragma unroll
    for (int nf = 0; nf < 4; ++nf) {
        int gcol = cbase + nf * 16 + (lane & 15);
        bool live = (gcol < V_) && (gcol != PAD_IDX_);
        float bb = (gcol < V_) ? bias[gcol] : 0.f;
#pragma unroll
        for (int mf = 0; mf < 4; ++mf) {
#pragma unroll
            for (int r = 0; r < 4; ++r) {
                float e = live ? __expf(acc[mf][nf][r] + bb) : 0.f;
                psum[mf][r] += e;
                int grow = rbase + mf * 16 + (lane >> 4) * 4 + r;
                if (E16) {
                    __bf16 h = (__bf16)e;
                    __builtin_nontemporal_store(*(const ushort*)&h,
                                                &E[(size_t)grow * VP_ + gcol]);
                } else if (gcol < V_) {
                    out[(size_t)grow * NC_ + gcol] = e;
                }
            }
        }
    }
#pragma unroll
    for (int off = 1; off < 16; off <<= 1)
#pragma unroll
        for (int mf = 0; mf < 4; ++mf)
#pragma unroll
            for (int r = 0; r < 4; ++r)
                psum[mf][r] += __shfl_xor(psum[mf][r], off);
    if ((lane & 15) == 0) {
        int pc = 2 * nb + wn;
#pragma unroll
        for (int mf = 0; mf < 4; ++mf)
#pragma unroll
            for (int r = 0; r < 4; ++r) {
                int grow = rbase + mf * 16 + (lane >> 4) * 4 + r;
                part[(size_t)grow * PSTRIDE + pc] = psum[mf][r];
            }
    }
}

// ---------------------------------------------------------------------------
// finish: rowsum from partials; out[n,0:V] = E*(1-c)/rowsum; out[n,V:] = copy
template<bool E16>
__global__ __launch_bounds__(256)
void k_finish(const ushort* __restrict__ E, const float* __restrict__ part,
              const float* __restrict__ cvec, const float* __restrict__ attn,
              const int* __restrict__ ids, float* __restrict__ out)
{
    int n = blockIdx.x;
    int tid = threadIdx.x;
    float c = cvec[n];
    float* row = out + (size_t)n * NC_;

    __shared__ float ws4[4];
    __shared__ float cp[CV_];
    if (tid < CV_) cp[tid] = 0.f;

    float s = 0.f;
    for (int p = tid; p < 2 * NB_; p += 256) s += part[(size_t)n * PSTRIDE + p];
#pragma unroll
    for (int off = 32; off; off >>= 1) s += __shfl_down(s, off);
    if ((tid & 63) == 0) ws4[tid >> 6] = s;
    __syncthreads();
    float rowsum = ws4[0] + ws4[1] + ws4[2] + ws4[3];
    float sc = (1.f - c) / rowsum;

    if (tid < S_) atomicAdd(&cp[ids[tid * B_ + (n & (B_ - 1))]],
                            attn[(size_t)n * S_ + tid] * c);

    if (E16) {
        const ushort* e = E + (size_t)n * VP_;
        for (int i = tid; i < V_ / 8; i += 256) {
            bf16x8 v = __builtin_nontemporal_load((const bf16x8*)(e + i * 8));
            f32x4 o0, o1;
            o0[0]=(float)v[0]*sc; o0[1]=(float)v[1]*sc; o0[2]=(float)v[2]*sc; o0[3]=(float)v[3]*sc;
            o1[0]=(float)v[4]*sc; o1[1]=(float)v[5]*sc; o1[2]=(float)v[6]*sc; o1[3]=(float)v[7]*sc;
            __builtin_nontemporal_store(o0, (f32x4*)(row + i * 8));
            __builtin_nontemporal_store(o1, (f32x4*)(row + i * 8 + 4));
        }
    } else {
        for (int i = tid; i < V_ / 4; i += 256) {
            f32x4 v = *(const f32x4*)(row + i * 4);
            v[0]*=sc; v[1]*=sc; v[2]*=sc; v[3]*=sc;
            *(f32x4*)(row + i * 4) = v;
        }
    }
    __syncthreads();
    if (tid < CV_) row[V_ + tid] = cp[tid];
}

// ---------------------------------------------------------------------------
extern "C" void kernel_launch(void* const* d_in, const int* in_sizes, int n_in,
                              void* d_out, int out_size, void* d_ws, size_t ws_size,
                              hipStream_t stream)
{
    const float* hidden  = (const float*)d_in[0];
    const float* attn    = (const float*)d_in[1];
    const float* src_map = (const float*)d_in[2];
    const float* W       = (const float*)d_in[3];
    const float* bias    = (const float*)d_in[4];
    const float* w_copy  = (const float*)d_in[5];
    const float* b_copy  = (const float*)d_in[6];
    float* out = (float*)d_out;

    // workspace layout
    size_t off = 0;
    __bf16* Wt = (__bf16*)((char*)d_ws + off); off += (size_t)VP_ * K_ * 2;
    __bf16* Ab = (__bf16*)((char*)d_ws + off); off += (size_t)M_ * K_ * 2;
    float* cvec = (float*)((char*)d_ws + off); off += M_ * 4;
    int*   ids  = (int*)((char*)d_ws + off);   off += 16384;
    float* part = (float*)((char*)d_ws + off); off += (size_t)M_ * PSTRIDE * 4;
    ushort* E   = (ushort*)((char*)d_ws + off);
    bool e16 = (off + (size_t)M_ * VP_ * 2) <= ws_size;

    k_prep<<<M_ / 4, 256, 0, stream>>>(hidden, w_copy, b_copy, Ab, cvec);
    k_wt<<<dim3(VP_ / 64, K_ / 64), 256, 0, stream>>>(W, Wt);
    k_ids<<<(S_ * B_ + 255) / 256, 256, 0, stream>>>(src_map, ids);

    dim3 gg(M_ / BM, VP_ / BN);
    if (e16) {
        k_gemm_exp<true><<<gg, 256, 0, stream>>>(Ab, Wt, bias, out, E, part);
        k_finish<true><<<M_, 256, 0, stream>>>(E, part, cvec, attn, ids, out);
    } else {
        k_gemm_exp<false><<<gg, 256, 0, stream>>>(Ab, Wt, bias, out, E, part);
        k_finish<false><<<M_, 256, 0, stream>>>((const ushort*)out, part, cvec, attn, ids, out);
    }
}

// Round 5
// 494.469 us; speedup vs baseline: 1.2740x; 1.2740x over previous
//
#include <hip/hip_runtime.h>
#include <hip/hip_bf16.h>
#include <math.h>

// Problem constants
#define M_ 2048
#define K_ 1024
#define V_ 50000
#define VP_ 50048        // V padded to 128
#define CV_ 120
#define NC_ (V_ + CV_)   // 50120 out row stride
#define S_ 100
#define B_ 32
#define PAD_IDX_ 1

// GEMM tiling
#define BM 128
#define BN 128
#define BK 32
#define NKT (K_ / BK)                   // 32 k-steps
#define NB_ (VP_ / BN)                  // 391 N-blocks
#define NWG_ ((M_ / BM) * NB_)          // 6256
#define WPX_ (NWG_ / 8)                 // 782 (exact)
#define PSTRIDE 800                     // partials row stride (2*NB_=782 used)

typedef float f32x4 __attribute__((ext_vector_type(4)));
typedef __bf16 bf16x8 __attribute__((ext_vector_type(8)));
typedef unsigned short ushort;

__device__ __forceinline__ void async_copy16(const void* g, void* l) {
    __builtin_amdgcn_global_load_lds(
        (const __attribute__((address_space(1))) void*)g,
        (__attribute__((address_space(3))) void*)l, 16, 0, 0);
}
// quarter-wave conflict-free chunk swizzle (verified r4: conflicts -> 0)
#define SIG(row) (((row) >> 1) & 3)

// ---------------------------------------------------------------------------
// fused: hidden->bf16 (plain row-major), copy gate. 1 wave per row.
__global__ __launch_bounds__(256)
void k_prep(const float* __restrict__ hidden, const float* __restrict__ w_copy,
            const float* __restrict__ b_copy, __bf16* __restrict__ Ab,
            float* __restrict__ cvec)
{
    int n = blockIdx.x * 4 + (threadIdx.x >> 6);
    int lane = threadIdx.x & 63;
    const float* h = hidden + (size_t)n * K_;
    __bf16* arow = Ab + (size_t)n * K_;
    float s = 0.f;
#pragma unroll
    for (int g = 0; g < 2; ++g) {
        int gg = 2 * lane + g;
        f32x4 a = *(const f32x4*)(h + gg * 8);
        f32x4 b = *(const f32x4*)(h + gg * 8 + 4);
        f32x4 wa = *(const f32x4*)(w_copy + gg * 8);
        f32x4 wb = *(const f32x4*)(w_copy + gg * 8 + 4);
        s += a[0]*wa[0] + a[1]*wa[1] + a[2]*wa[2] + a[3]*wa[3]
           + b[0]*wb[0] + b[1]*wb[1] + b[2]*wb[2] + b[3]*wb[3];
        bf16x8 v;
        v[0]=(__bf16)a[0]; v[1]=(__bf16)a[1]; v[2]=(__bf16)a[2]; v[3]=(__bf16)a[3];
        v[4]=(__bf16)b[0]; v[5]=(__bf16)b[1]; v[6]=(__bf16)b[2]; v[7]=(__bf16)b[3];
        *(bf16x8*)(arow + gg * 8) = v;
    }
#pragma unroll
    for (int off = 32; off; off >>= 1) s += __shfl_down(s, off);
    if (lane == 0) cvec[n] = 1.f / (1.f + __expf(-(s + b_copy[0])));
}

// ---------------------------------------------------------------------------
// W [K][V] fp32 -> Wt [VP][K] bf16, transposed; pad rows zeroed
__global__ __launch_bounds__(256)
void k_wt(const float* __restrict__ W, __bf16* __restrict__ Wt)
{
    __shared__ __bf16 t[64][72];
    int v0 = blockIdx.x * 64;
    int k0 = blockIdx.y * 64;
    int tid = threadIdx.x;
    int kr = tid >> 4;
    int vq = tid & 15;
    int v4 = v0 + vq * 4;
#pragma unroll
    for (int i = 0; i < 4; ++i) {
        int k = k0 + kr + i * 16;
        f32x4 val = {};
        if (v4 < V_) val = *(const f32x4*)(W + (size_t)k * V_ + v4);
#pragma unroll
        for (int c = 0; c < 4; ++c) t[vq * 4 + c][kr + i * 16] = (__bf16)val[c];
    }
    __syncthreads();
    int vr = tid >> 2;
    int q  = tid & 3;
    __bf16* dst = Wt + (size_t)(v0 + vr) * K_ + k0;
#pragma unroll
    for (int i = 0; i < 2; ++i) {
        bf16x8 o;
#pragma unroll
        for (int e = 0; e < 8; ++e) o[e] = t[vr][q * 8 + i * 32 + e];
        *(bf16x8*)(dst + q * 8 + i * 32) = o;
    }
}

// ---------------------------------------------------------------------------
// one-hot src_map -> integer ids [S*B]
__global__ __launch_bounds__(256)
void k_ids(const float* __restrict__ src_map, int* __restrict__ ids)
{
    int i = blockIdx.x * 256 + threadIdx.x;
    if (i < S_ * B_) {
        const float* r = src_map + (size_t)i * CV_;
        int id = 0;
        for (int v = 0; v < CV_; ++v)
            if (r[v] > 0.5f) { id = v; break; }
        ids[i] = id;
    }
}

// ---------------------------------------------------------------------------
// GEMM: e = exp(A.Wt^T + b) (PAD col->0); bf16 E store; per-block row partials.
// 3-buf pipeline, counted vmcnt(4), raw s_barrier (loads span barriers).
template<bool E16>
__global__ __launch_bounds__(256, 3)
void k_gemm_exp(const __bf16* __restrict__ A, const __bf16* __restrict__ Bt,
                const float* __restrict__ bias, float* __restrict__ out,
                ushort* __restrict__ E, float* __restrict__ part)
{
    __shared__ __bf16 lds[3 * 2 * BM * BK];   // 3 bufs x (A 8KB + B 8KB) = 48 KB

    const int tid  = threadIdx.x;
    const int lane = tid & 63;
    const int wid  = tid >> 6;
    const int wm   = wid >> 1;
    const int wn   = wid & 1;

    // bijective XCD swizzle: 6256 = 8 * 782
    int orig = blockIdx.y * (M_ / BM) + blockIdx.x;
    int nid  = (orig & 7) * WPX_ + (orig >> 3);
    const int m0 = (nid & 15) * BM;
    const int nb = nid >> 4;
    const int n0 = nb * BN;

    f32x4 acc[4][4] = {};

#define STAGE(d, kt)                                                          \
    do {                                                                      \
        _Pragma("unroll")                                                     \
        for (int j = 0; j < 2; ++j) {                                         \
            int g = j * 256 + tid; int row = g >> 2;                          \
            int ch = (g & 3) ^ SIG(row);                                      \
            async_copy16(A + (size_t)(m0 + row) * K_ + (kt) * BK + ch * 8,    \
                         &lds[(d) * 8192 + (j * 256 + wid * 64) * 8]);        \
        }                                                                     \
        _Pragma("unroll")                                                     \
        for (int j = 0; j < 2; ++j) {                                         \
            int g = j * 256 + tid; int row = g >> 2;                          \
            int ch = (g & 3) ^ SIG(row);                                      \
            async_copy16(Bt + (size_t)(n0 + row) * K_ + (kt) * BK + ch * 8,   \
                         &lds[(d) * 8192 + 4096 + (j * 256 + wid * 64) * 8]); \
        }                                                                     \
    } while (0)

    STAGE(0, 0);
    STAGE(1, 1);

    const int chx = (((lane >> 4) ^ ((lane >> 1) & 3))) * 8;
    int cur = 0;
    for (int kt = 0; kt < NKT; ++kt) {
        __builtin_amdgcn_sched_barrier(0);      // pin prior ds_reads above
        if (kt < NKT - 1) asm volatile("s_waitcnt vmcnt(4)" ::: "memory");
        else              asm volatile("s_waitcnt vmcnt(0)" ::: "memory");
        __builtin_amdgcn_s_barrier();           // all waves: S_kt landed; buf(kt-1) reads done
        __builtin_amdgcn_sched_barrier(0);
        if (kt < NKT - 2) {
            int nxt = cur + 2; if (nxt >= 3) nxt -= 3;
            STAGE(nxt, kt + 2);
        }
        const __bf16* bufA = &lds[cur * 8192];
        const __bf16* bufB = bufA + 4096;
        bf16x8 fa[4], fb[4];
#pragma unroll
        for (int mf = 0; mf < 4; ++mf)
            fa[mf] = *(const bf16x8*)(&bufA[(wm * 64 + mf * 16 + (lane & 15)) * BK + chx]);
#pragma unroll
        for (int nf = 0; nf < 4; ++nf)
            fb[nf] = *(const bf16x8*)(&bufB[(wn * 64 + nf * 16 + (lane & 15)) * BK + chx]);
#pragma unroll
        for (int mf = 0; mf < 4; ++mf)
#pragma unroll
            for (int nf = 0; nf < 4; ++nf)
                acc[mf][nf] = __builtin_amdgcn_mfma_f32_16x16x32_bf16(
                    fa[mf], fb[nf], acc[mf][nf], 0, 0, 0);
        cur += 1; if (cur >= 3) cur -= 3;
    }
#undef STAGE

    __builtin_amdgcn_s_barrier();   // main loop fully done before LDS reuse

    // epilogue: bias + exp + psum; stage E tile in LDS; coalesced 16B stores
    const int rbase = m0 + wm * 64;
    const int cbase = n0 + wn * 64;
    ushort* Els = (ushort*)lds + wid * 64 * 72;   // 64x64 per wave, stride 72
    float psum[4][4] = {};
#pragma unroll
    for (int nf = 0; nf < 4; ++nf) {
        int gcol = cbase + nf * 16 + (lane & 15);
        bool live = (gcol < V_) && (gcol != PAD_IDX_);
        float bb = (gcol < V_) ? bias[gcol] : 0.f;
#pragma unroll
        for (int mf = 0; mf < 4; ++mf) {
#pragma unroll
            for (int r = 0; r < 4; ++r) {
                float e = live ? __expf(acc[mf][nf][r] + bb) : 0.f;
                psum[mf][r] += e;
                if (E16) {
                    __bf16 h = (__bf16)e;
                    Els[(mf * 16 + (lane >> 4) * 4 + r) * 72 + nf * 16 + (lane & 15)]
                        = *(const ushort*)&h;
                } else {
                    int grow = rbase + mf * 16 + (lane >> 4) * 4 + r;
                    if (gcol < V_) out[(size_t)grow * NC_ + gcol] = e;
                }
            }
        }
    }
    if (E16) {
        // rows 8-per-pass: lane -> row p*8+(lane>>3), 16B chunk (lane&7)
#pragma unroll
        for (int p = 0; p < 8; ++p) {
            int row_l = p * 8 + (lane >> 3);
            int g = lane & 7;
            bf16x8 v = *(const bf16x8*)(&Els[row_l * 72 + g * 8]);
            __builtin_nontemporal_store(
                v, (bf16x8*)&E[(size_t)(rbase + row_l) * VP_ + cbase + g * 8]);
        }
    }
#pragma unroll
    for (int off = 1; off < 16; off <<= 1)
#pragma unroll
        for (int mf = 0; mf < 4; ++mf)
#pragma unroll
            for (int r = 0; r < 4; ++r)
                psum[mf][r] += __shfl_xor(psum[mf][r], off);
    if ((lane & 15) == 0) {
        int pc = 2 * nb + wn;
#pragma unroll
        for (int mf = 0; mf < 4; ++mf)
#pragma unroll
            for (int r = 0; r < 4; ++r) {
                int grow = rbase + mf * 16 + (lane >> 4) * 4 + r;
                part[(size_t)grow * PSTRIDE + pc] = psum[mf][r];
            }
    }
}

// ---------------------------------------------------------------------------
// finish: rowsum from partials; out[n,0:V] = E*(1-c)/rowsum; out[n,V:] = copy
// 2 blocks per row (V split) for latency hiding.
template<bool E16>
__global__ __launch_bounds__(256)
void k_finish(const ushort* __restrict__ E, const float* __restrict__ part,
              const float* __restrict__ cvec, const float* __restrict__ attn,
              const int* __restrict__ ids, float* __restrict__ out)
{
    int n = blockIdx.y;
    int half = blockIdx.x;
    int tid = threadIdx.x;
    float c = cvec[n];
    float* row = out + (size_t)n * NC_;

    __shared__ float ws4[4];
    __shared__ float cp[CV_];
    if (half == 1 && tid < CV_) cp[tid] = 0.f;

    float s = 0.f;
    for (int p = tid; p < 2 * NB_; p += 256) s += part[(size_t)n * PSTRIDE + p];
#pragma unroll
    for (int off = 32; off; off >>= 1) s += __shfl_down(s, off);
    if ((tid & 63) == 0) ws4[tid >> 6] = s;
    __syncthreads();
    float rowsum = ws4[0] + ws4[1] + ws4[2] + ws4[3];
    float sc = (1.f - c) / rowsum;

    if (half == 1 && tid < S_)
        atomicAdd(&cp[ids[tid * B_ + (n & (B_ - 1))]],
                  attn[(size_t)n * S_ + tid] * c);

    if (E16) {
        const ushort* e = E + (size_t)n * VP_;
        for (int i = half * 3125 + tid; i < (half + 1) * 3125; i += 256) {
            bf16x8 v = __builtin_nontemporal_load((const bf16x8*)(e + i * 8));
            f32x4 o0, o1;
            o0[0]=(float)v[0]*sc; o0[1]=(float)v[1]*sc; o0[2]=(float)v[2]*sc; o0[3]=(float)v[3]*sc;
            o1[0]=(float)v[4]*sc; o1[1]=(float)v[5]*sc; o1[2]=(float)v[6]*sc; o1[3]=(float)v[7]*sc;
            __builtin_nontemporal_store(o0, (f32x4*)(row + i * 8));
            __builtin_nontemporal_store(o1, (f32x4*)(row + i * 8 + 4));
        }
    } else {
        for (int i = half * 6250 + tid; i < (half + 1) * 6250; i += 256) {
            f32x4 v = *(const f32x4*)(row + i * 4);
            v[0]*=sc; v[1]*=sc; v[2]*=sc; v[3]*=sc;
            *(f32x4*)(row + i * 4) = v;
        }
    }
    if (half == 1) {
        __syncthreads();
        if (tid < CV_) row[V_ + tid] = cp[tid];
    }
}

// ---------------------------------------------------------------------------
extern "C" void kernel_launch(void* const* d_in, const int* in_sizes, int n_in,
                              void* d_out, int out_size, void* d_ws, size_t ws_size,
                              hipStream_t stream)
{
    const float* hidden  = (const float*)d_in[0];
    const float* attn    = (const float*)d_in[1];
    const float* src_map = (const float*)d_in[2];
    const float* W       = (const float*)d_in[3];
    const float* bias    = (const float*)d_in[4];
    const float* w_copy  = (const float*)d_in[5];
    const float* b_copy  = (const float*)d_in[6];
    float* out = (float*)d_out;

    // workspace layout
    size_t off = 0;
    __bf16* Wt = (__bf16*)((char*)d_ws + off); off += (size_t)VP_ * K_ * 2;
    __bf16* Ab = (__bf16*)((char*)d_ws + off); off += (size_t)M_ * K_ * 2;
    float* cvec = (float*)((char*)d_ws + off); off += M_ * 4;
    int*   ids  = (int*)((char*)d_ws + off);   off += 16384;
    float* part = (float*)((char*)d_ws + off); off += (size_t)M_ * PSTRIDE * 4;
    ushort* E   = (ushort*)((char*)d_ws + off);
    bool e16 = (off + (size_t)M_ * VP_ * 2) <= ws_size;

    k_prep<<<M_ / 4, 256, 0, stream>>>(hidden, w_copy, b_copy, Ab, cvec);
    k_wt<<<dim3(VP_ / 64, K_ / 64), 256, 0, stream>>>(W, Wt);
    k_ids<<<(S_ * B_ + 255) / 256, 256, 0, stream>>>(src_map, ids);

    dim3 gg(M_ / BM, VP_ / BN);
    dim3 gf(2, M_);
    if (e16) {
        k_gemm_exp<true><<<gg, 256, 0, stream>>>(Ab, Wt, bias, out, E, part);
        k_finish<true><<<gf, 256, 0, stream>>>(E, part, cvec, attn, ids, out);
    } else {
        k_gemm_exp<false><<<gg, 256, 0, stream>>>(Ab, Wt, bias, out, E, part);
        k_finish<false><<<gf, 256, 0, stream>>>((const ushort*)out, part, cvec, attn, ids, out);
    }
}

// Round 6
// 471.652 us; speedup vs baseline: 1.3356x; 1.0484x over previous
//
#include <hip/hip_runtime.h>
#include <hip/hip_bf16.h>
#include <math.h>

// Problem constants
#define M_ 2048
#define K_ 1024
#define V_ 50000
#define VP_ 50048        // V padded to 128
#define CV_ 120
#define NC_ (V_ + CV_)   // 50120 out row stride
#define S_ 100
#define B_ 32
#define PAD_IDX_ 1

// GEMM tiling: block 256x128, 4 waves stacked in M, wave tile 64x128
#define BM 256
#define BN 128
#define BK 32
#define NKT (K_ / BK)                   // 32 k-steps
#define NB_ (VP_ / BN)                  // 391 N-blocks
#define NMT (M_ / BM)                   // 8 M-blocks
#define NWG_ (NMT * NB_)                // 3128 = 8 * 391
#define WPX_ (NWG_ / 8)                 // 391 (exact)
#define PSTRIDE 400                     // partials row stride (NB_=391 used)
#define BUFE 12288                      // bf16 elems per pipeline buf (24 KB)

typedef float f32x4 __attribute__((ext_vector_type(4)));
typedef __bf16 bf16x8 __attribute__((ext_vector_type(8)));
typedef unsigned short ushort;

__device__ __forceinline__ void async_copy16(const void* g, void* l) {
    __builtin_amdgcn_global_load_lds(
        (const __attribute__((address_space(1))) void*)g,
        (__attribute__((address_space(3))) void*)l, 16, 0, 0);
}
// quarter-wave conflict-free chunk swizzle (verified r4: conflicts -> 0)
#define SIG(row) (((row) >> 1) & 3)

// ---------------------------------------------------------------------------
// fused: hidden->bf16 (plain row-major), copy gate. 1 wave per row.
__global__ __launch_bounds__(256)
void k_prep(const float* __restrict__ hidden, const float* __restrict__ w_copy,
            const float* __restrict__ b_copy, __bf16* __restrict__ Ab,
            float* __restrict__ cvec)
{
    int n = blockIdx.x * 4 + (threadIdx.x >> 6);
    int lane = threadIdx.x & 63;
    const float* h = hidden + (size_t)n * K_;
    __bf16* arow = Ab + (size_t)n * K_;
    float s = 0.f;
#pragma unroll
    for (int g = 0; g < 2; ++g) {
        int gg = 2 * lane + g;
        f32x4 a = *(const f32x4*)(h + gg * 8);
        f32x4 b = *(const f32x4*)(h + gg * 8 + 4);
        f32x4 wa = *(const f32x4*)(w_copy + gg * 8);
        f32x4 wb = *(const f32x4*)(w_copy + gg * 8 + 4);
        s += a[0]*wa[0] + a[1]*wa[1] + a[2]*wa[2] + a[3]*wa[3]
           + b[0]*wb[0] + b[1]*wb[1] + b[2]*wb[2] + b[3]*wb[3];
        bf16x8 v;
        v[0]=(__bf16)a[0]; v[1]=(__bf16)a[1]; v[2]=(__bf16)a[2]; v[3]=(__bf16)a[3];
        v[4]=(__bf16)b[0]; v[5]=(__bf16)b[1]; v[6]=(__bf16)b[2]; v[7]=(__bf16)b[3];
        *(bf16x8*)(arow + gg * 8) = v;
    }
#pragma unroll
    for (int off = 32; off; off >>= 1) s += __shfl_down(s, off);
    if (lane == 0) cvec[n] = 1.f / (1.f + __expf(-(s + b_copy[0])));
}

// ---------------------------------------------------------------------------
// W [K][V] fp32 -> Wt [VP][K] bf16, transposed; pad rows zeroed
__global__ __launch_bounds__(256)
void k_wt(const float* __restrict__ W, __bf16* __restrict__ Wt)
{
    __shared__ __bf16 t[64][72];
    int v0 = blockIdx.x * 64;
    int k0 = blockIdx.y * 64;
    int tid = threadIdx.x;
    int kr = tid >> 4;
    int vq = tid & 15;
    int v4 = v0 + vq * 4;
#pragma unroll
    for (int i = 0; i < 4; ++i) {
        int k = k0 + kr + i * 16;
        f32x4 val = {};
        if (v4 < V_) val = *(const f32x4*)(W + (size_t)k * V_ + v4);
#pragma unroll
        for (int c = 0; c < 4; ++c) t[vq * 4 + c][kr + i * 16] = (__bf16)val[c];
    }
    __syncthreads();
    int vr = tid >> 2;
    int q  = tid & 3;
    __bf16* dst = Wt + (size_t)(v0 + vr) * K_ + k0;
#pragma unroll
    for (int i = 0; i < 2; ++i) {
        bf16x8 o;
#pragma unroll
        for (int e = 0; e < 8; ++e) o[e] = t[vr][q * 8 + i * 32 + e];
        *(bf16x8*)(dst + q * 8 + i * 32) = o;
    }
}

// ---------------------------------------------------------------------------
// one-hot src_map -> integer ids [S*B]
__global__ __launch_bounds__(256)
void k_ids(const float* __restrict__ src_map, int* __restrict__ ids)
{
    int i = blockIdx.x * 256 + threadIdx.x;
    if (i < S_ * B_) {
        const float* r = src_map + (size_t)i * CV_;
        int id = 0;
        for (int v = 0; v < CV_; ++v)
            if (r[v] > 0.5f) { id = v; break; }
        ids[i] = id;
    }
}

// ---------------------------------------------------------------------------
// GEMM: e = exp(A.Wt^T + b) (PAD col->0); bf16 E store; per-block row partials.
// 3-buf pipeline, counted vmcnt(6), raw s_barrier, setprio around MFMA.
template<bool E16>
__global__ __launch_bounds__(256, 2)
void k_gemm_exp(const __bf16* __restrict__ A, const __bf16* __restrict__ Bt,
                const float* __restrict__ bias, float* __restrict__ out,
                ushort* __restrict__ E, float* __restrict__ part)
{
    __shared__ __bf16 lds[3 * BUFE];   // 3 bufs x (A 16KB + B 8KB) = 72 KB

    const int tid  = threadIdx.x;
    const int lane = tid & 63;
    const int wid  = tid >> 6;

    // bijective XCD swizzle: 3128 = 8 * 391
    int orig = blockIdx.y * NMT + blockIdx.x;
    int nid  = (orig & 7) * WPX_ + (orig >> 3);
    const int m0 = (nid & 7) * BM;    // m fastest within an XCD's chunk
    const int nb = nid >> 3;
    const int n0 = nb * BN;

    f32x4 acc[4][8] = {};

#define STAGE(d, kt)                                                          \
    do {                                                                      \
        _Pragma("unroll")                                                     \
        for (int j = 0; j < 4; ++j) {                                         \
            int g = j * 256 + tid; int row = g >> 2;                          \
            int ch = (g & 3) ^ SIG(row);                                      \
            async_copy16(A + (size_t)(m0 + row) * K_ + (kt) * BK + ch * 8,    \
                         &lds[(d) * BUFE + (j * 256 + wid * 64) * 8]);        \
        }                                                                     \
        _Pragma("unroll")                                                     \
        for (int j = 0; j < 2; ++j) {                                         \
            int g = j * 256 + tid; int row = g >> 2;                          \
            int ch = (g & 3) ^ SIG(row);                                      \
            async_copy16(Bt + (size_t)(n0 + row) * K_ + (kt) * BK + ch * 8,   \
                         &lds[(d) * BUFE + 8192 + (j * 256 + wid * 64) * 8]); \
        }                                                                     \
    } while (0)

    STAGE(0, 0);
    STAGE(1, 1);

    const int chx = (((lane >> 4) ^ ((lane >> 1) & 3))) * 8;
    int cur = 0;
    for (int kt = 0; kt < NKT; ++kt) {
        __builtin_amdgcn_sched_barrier(0);
        if (kt < NKT - 1) asm volatile("s_waitcnt vmcnt(6)" ::: "memory");
        else              asm volatile("s_waitcnt vmcnt(0)" ::: "memory");
        __builtin_amdgcn_s_barrier();           // S_kt landed; buf(kt-1) reads done
        __builtin_amdgcn_sched_barrier(0);
        if (kt < NKT - 2) {
            int nxt = cur + 2; if (nxt >= 3) nxt -= 3;
            STAGE(nxt, kt + 2);
        }
        const __bf16* bufA = &lds[cur * BUFE];
        const __bf16* bufB = bufA + 8192;
        bf16x8 fa[4], fb[8];
#pragma unroll
        for (int mf = 0; mf < 4; ++mf)
            fa[mf] = *(const bf16x8*)(&bufA[(wid * 64 + mf * 16 + (lane & 15)) * BK + chx]);
#pragma unroll
        for (int nf = 0; nf < 8; ++nf)
            fb[nf] = *(const bf16x8*)(&bufB[(nf * 16 + (lane & 15)) * BK + chx]);
        __builtin_amdgcn_s_setprio(1);
#pragma unroll
        for (int mf = 0; mf < 4; ++mf)
#pragma unroll
            for (int nf = 0; nf < 8; ++nf)
                acc[mf][nf] = __builtin_amdgcn_mfma_f32_16x16x32_bf16(
                    fa[mf], fb[nf], acc[mf][nf], 0, 0, 0);
        __builtin_amdgcn_s_setprio(0);
        cur += 1; if (cur >= 3) cur -= 3;
    }
#undef STAGE

    __builtin_amdgcn_s_barrier();   // main loop fully done before LDS reuse

    // epilogue: bias + exp + psum; stage wave's 64x128 E tile in LDS (stride 136)
    const int rbase = m0 + wid * 64;
    float psum[4][4] = {};
    ushort* Els = (ushort*)lds + wid * 64 * 136;
#pragma unroll
    for (int nf = 0; nf < 8; ++nf) {
        int gcol = n0 + nf * 16 + (lane & 15);
        bool live = (gcol < V_) && (gcol != PAD_IDX_);
        float bb = (gcol < V_) ? bias[gcol] : 0.f;
#pragma unroll
        for (int mf = 0; mf < 4; ++mf) {
#pragma unroll
            for (int r = 0; r < 4; ++r) {
                float e = live ? __expf(acc[mf][nf][r] + bb) : 0.f;
                psum[mf][r] += e;
                if (E16) {
                    __bf16 h = (__bf16)e;
                    Els[(mf * 16 + (lane >> 4) * 4 + r) * 136 + nf * 16 + (lane & 15)]
                        = *(const ushort*)&h;
                } else {
                    int grow = rbase + mf * 16 + (lane >> 4) * 4 + r;
                    if (gcol < V_) out[(size_t)grow * NC_ + gcol] = e;
                }
            }
        }
    }
    if (E16) {
        // 16 passes: 4 rows x 256B coalesced segments per pass
#pragma unroll
        for (int p = 0; p < 16; ++p) {
            int row_l = p * 4 + (lane >> 4);
            int g = lane & 15;
            bf16x8 v = *(const bf16x8*)(&Els[row_l * 136 + g * 8]);
            __builtin_nontemporal_store(
                v, (bf16x8*)&E[(size_t)(rbase + row_l) * VP_ + n0 + g * 8]);
        }
    }
#pragma unroll
    for (int off = 1; off < 16; off <<= 1)
#pragma unroll
        for (int mf = 0; mf < 4; ++mf)
#pragma unroll
            for (int r = 0; r < 4; ++r)
                psum[mf][r] += __shfl_xor(psum[mf][r], off);
    if ((lane & 15) == 0) {
#pragma unroll
        for (int mf = 0; mf < 4; ++mf)
#pragma unroll
            for (int r = 0; r < 4; ++r) {
                int grow = rbase + mf * 16 + (lane >> 4) * 4 + r;
                part[(size_t)grow * PSTRIDE + nb] = psum[mf][r];
            }
    }
}

// ---------------------------------------------------------------------------
// finish: rowsum from partials; out[n,0:V] = E*(1-c)/rowsum; out[n,V:] = copy
// 2 blocks per row (V split).
template<bool E16>
__global__ __launch_bounds__(256)
void k_finish(const ushort* __restrict__ E, const float* __restrict__ part,
              const float* __restrict__ cvec, const float* __restrict__ attn,
              const int* __restrict__ ids, float* __restrict__ out)
{
    int n = blockIdx.y;
    int half = blockIdx.x;
    int tid = threadIdx.x;
    float c = cvec[n];
    float* row = out + (size_t)n * NC_;

    __shared__ float ws4[4];
    __shared__ float cp[CV_];
    if (half == 1 && tid < CV_) cp[tid] = 0.f;

    float s = 0.f;
    for (int p = tid; p < NB_; p += 256) s += part[(size_t)n * PSTRIDE + p];
#pragma unroll
    for (int off = 32; off; off >>= 1) s += __shfl_down(s, off);
    if ((tid & 63) == 0) ws4[tid >> 6] = s;
    __syncthreads();
    float rowsum = ws4[0] + ws4[1] + ws4[2] + ws4[3];
    float sc = (1.f - c) / rowsum;

    if (half == 1 && tid < S_)
        atomicAdd(&cp[ids[tid * B_ + (n & (B_ - 1))]],
                  attn[(size_t)n * S_ + tid] * c);

    if (E16) {
        const ushort* e = E + (size_t)n * VP_;
        for (int i = half * 3125 + tid; i < (half + 1) * 3125; i += 256) {
            bf16x8 v = __builtin_nontemporal_load((const bf16x8*)(e + i * 8));
            f32x4 o0, o1;
            o0[0]=(float)v[0]*sc; o0[1]=(float)v[1]*sc; o0[2]=(float)v[2]*sc; o0[3]=(float)v[3]*sc;
            o1[0]=(float)v[4]*sc; o1[1]=(float)v[5]*sc; o1[2]=(float)v[6]*sc; o1[3]=(float)v[7]*sc;
            __builtin_nontemporal_store(o0, (f32x4*)(row + i * 8));
            __builtin_nontemporal_store(o1, (f32x4*)(row + i * 8 + 4));
        }
    } else {
        for (int i = half * 6250 + tid; i < (half + 1) * 6250; i += 256) {
            f32x4 v = *(const f32x4*)(row + i * 4);
            v[0]*=sc; v[1]*=sc; v[2]*=sc; v[3]*=sc;
            *(f32x4*)(row + i * 4) = v;
        }
    }
    if (half == 1) {
        __syncthreads();
        if (tid < CV_) row[V_ + tid] = cp[tid];
    }
}

// ---------------------------------------------------------------------------
extern "C" void kernel_launch(void* const* d_in, const int* in_sizes, int n_in,
                              void* d_out, int out_size, void* d_ws, size_t ws_size,
                              hipStream_t stream)
{
    const float* hidden  = (const float*)d_in[0];
    const float* attn    = (const float*)d_in[1];
    const float* src_map = (const float*)d_in[2];
    const float* W       = (const float*)d_in[3];
    const float* bias    = (const float*)d_in[4];
    const float* w_copy  = (const float*)d_in[5];
    const float* b_copy  = (const float*)d_in[6];
    float* out = (float*)d_out;

    // workspace layout
    size_t off = 0;
    __bf16* Wt = (__bf16*)((char*)d_ws + off); off += (size_t)VP_ * K_ * 2;
    __bf16* Ab = (__bf16*)((char*)d_ws + off); off += (size_t)M_ * K_ * 2;
    float* cvec = (float*)((char*)d_ws + off); off += M_ * 4;
    int*   ids  = (int*)((char*)d_ws + off);   off += 16384;
    float* part = (float*)((char*)d_ws + off); off += (size_t)M_ * PSTRIDE * 4;
    ushort* E   = (ushort*)((char*)d_ws + off);
    bool e16 = (off + (size_t)M_ * VP_ * 2) <= ws_size;

    k_prep<<<M_ / 4, 256, 0, stream>>>(hidden, w_copy, b_copy, Ab, cvec);
    k_wt<<<dim3(VP_ / 64, K_ / 64), 256, 0, stream>>>(W, Wt);
    k_ids<<<(S_ * B_ + 255) / 256, 256, 0, stream>>>(src_map, ids);

    dim3 gg(NMT, NB_);
    dim3 gf(2, M_);
    if (e16) {
        k_gemm_exp<true><<<gg, 256, 0, stream>>>(Ab, Wt, bias, out, E, part);
        k_finish<true><<<gf, 256, 0, stream>>>(E, part, cvec, attn, ids, out);
    } else {
        k_gemm_exp<false><<<gg, 256, 0, stream>>>(Ab, Wt, bias, out, E, part);
        k_finish<false><<<gf, 256, 0, stream>>>((const ushort*)out, part, cvec, attn, ids, out);
    }
}

// Round 7
// 454.892 us; speedup vs baseline: 1.3848x; 1.0368x over previous
//
#include <hip/hip_runtime.h>
#include <hip/hip_bf16.h>
#include <math.h>

// Problem constants
#define M_ 2048
#define K_ 1024
#define V_ 50000
#define VP_ 50048        // V padded to 128
#define CV_ 120
#define NC_ (V_ + CV_)   // 50120 out row stride
#define S_ 100
#define B_ 32
#define PAD_IDX_ 1

// GEMM tiling: block 256x128, 4 waves stacked in M, wave tile 64x128
#define BM 256
#define BN 128
#define BK 32
#define NKT (K_ / BK)                   // 32 k-steps
#define NB_ (VP_ / BN)                  // 391 N-blocks
#define NMT (M_ / BM)                   // 8 M-blocks
#define NWG_ (NMT * NB_)                // 3128 = 8 * 391
#define WPX_ (NWG_ / 8)                 // 391 (exact)
#define PSTRIDE 400                     // partials row stride (NB_=391 used)
#define BUFE 12288                      // bf16 elems per pipeline buf (24 KB)

// merged pre-kernel block ranges
#define WT_BLKS (782 * 16)              // 12512
#define PREP_BLKS (M_ / 4)              // 512
#define IDS_BLKS (((S_ * B_) + 255) / 256) // 13

typedef float f32x4 __attribute__((ext_vector_type(4)));
typedef __bf16 bf16x8 __attribute__((ext_vector_type(8)));
typedef unsigned short ushort;

__device__ __forceinline__ void async_copy16(const void* g, void* l) {
    __builtin_amdgcn_global_load_lds(
        (const __attribute__((address_space(1))) void*)g,
        (__attribute__((address_space(3))) void*)l, 16, 0, 0);
}
// quarter-wave conflict-free chunk swizzle (verified r4: conflicts -> 0)
#define SIG(row) (((row) >> 1) & 3)

// ---------------------------------------------------------------------------
// merged pre-pass: [0,WT_BLKS) W-transpose; [WT,+PREP) hidden->bf16 + copy
// gate; [+PREP,+IDS) one-hot -> ids.
__global__ __launch_bounds__(256)
void k_pre(const float* __restrict__ W, __bf16* __restrict__ Wt,
           const float* __restrict__ hidden, const float* __restrict__ w_copy,
           const float* __restrict__ b_copy, __bf16* __restrict__ Ab,
           float* __restrict__ cvec, const float* __restrict__ src_map,
           int* __restrict__ ids)
{
    int bx = blockIdx.x;
    int tid = threadIdx.x;
    if (bx < WT_BLKS) {
        // ---- W [K][V] fp32 -> Wt [VP][K] bf16 (64x64 tile transpose)
        __shared__ __bf16 t[64][72];
        int v0 = (bx % 782) * 64;
        int k0 = (bx / 782) * 64;
        int kr = tid >> 4;
        int vq = tid & 15;
        int v4 = v0 + vq * 4;
#pragma unroll
        for (int i = 0; i < 4; ++i) {
            int k = k0 + kr + i * 16;
            f32x4 val = {};
            if (v4 < V_) val = *(const f32x4*)(W + (size_t)k * V_ + v4);
#pragma unroll
            for (int c = 0; c < 4; ++c) t[vq * 4 + c][kr + i * 16] = (__bf16)val[c];
        }
        __syncthreads();
        int vr = tid >> 2;
        int q  = tid & 3;
        __bf16* dst = Wt + (size_t)(v0 + vr) * K_ + k0;
#pragma unroll
        for (int i = 0; i < 2; ++i) {
            bf16x8 o;
#pragma unroll
            for (int e = 0; e < 8; ++e) o[e] = t[vr][q * 8 + i * 32 + e];
            *(bf16x8*)(dst + q * 8 + i * 32) = o;
        }
    } else if (bx < WT_BLKS + PREP_BLKS) {
        // ---- hidden->bf16 + copy gate. 1 wave per row.
        int n = (bx - WT_BLKS) * 4 + (tid >> 6);
        int lane = tid & 63;
        const float* h = hidden + (size_t)n * K_;
        __bf16* arow = Ab + (size_t)n * K_;
        float s = 0.f;
#pragma unroll
        for (int g = 0; g < 2; ++g) {
            int gg = 2 * lane + g;
            f32x4 a = *(const f32x4*)(h + gg * 8);
            f32x4 b = *(const f32x4*)(h + gg * 8 + 4);
            f32x4 wa = *(const f32x4*)(w_copy + gg * 8);
            f32x4 wb = *(const f32x4*)(w_copy + gg * 8 + 4);
            s += a[0]*wa[0] + a[1]*wa[1] + a[2]*wa[2] + a[3]*wa[3]
               + b[0]*wb[0] + b[1]*wb[1] + b[2]*wb[2] + b[3]*wb[3];
            bf16x8 v;
            v[0]=(__bf16)a[0]; v[1]=(__bf16)a[1]; v[2]=(__bf16)a[2]; v[3]=(__bf16)a[3];
            v[4]=(__bf16)b[0]; v[5]=(__bf16)b[1]; v[6]=(__bf16)b[2]; v[7]=(__bf16)b[3];
            *(bf16x8*)(arow + gg * 8) = v;
        }
#pragma unroll
        for (int off = 32; off; off >>= 1) s += __shfl_down(s, off);
        if (lane == 0) cvec[n] = 1.f / (1.f + __expf(-(s + b_copy[0])));
    } else {
        // ---- one-hot src_map -> integer ids [S*B]
        int i = (bx - WT_BLKS - PREP_BLKS) * 256 + tid;
        if (i < S_ * B_) {
            const float* r = src_map + (size_t)i * CV_;
            int id = 0;
            for (int v = 0; v < CV_; ++v)
                if (r[v] > 0.5f) { id = v; break; }
            ids[i] = id;
        }
    }
}

// ---------------------------------------------------------------------------
// GEMM: e = exp(A.Wt^T + b) (PAD col->0); bf16 E store; per-block row partials.
// 3-buf pipeline, counted vmcnt(6), raw s_barrier, setprio, 2-sub-phase body.
template<bool E16>
__global__ __launch_bounds__(256, 2)
void k_gemm_exp(const __bf16* __restrict__ A, const __bf16* __restrict__ Bt,
                const float* __restrict__ bias, float* __restrict__ out,
                ushort* __restrict__ E, float* __restrict__ part)
{
    __shared__ __bf16 lds[3 * BUFE];   // 3 bufs x (A 16KB + B 8KB) = 72 KB

    const int tid  = threadIdx.x;
    const int lane = tid & 63;
    const int wid  = tid >> 6;

    // bijective XCD swizzle: 3128 = 8 * 391
    int orig = blockIdx.y * NMT + blockIdx.x;
    int nid  = (orig & 7) * WPX_ + (orig >> 3);
    const int m0 = (nid & 7) * BM;    // m fastest within an XCD's chunk
    const int nb = nid >> 3;
    const int n0 = nb * BN;

    f32x4 acc[4][8] = {};

#define STAGE_A(d, kt)                                                        \
    do {                                                                      \
        _Pragma("unroll")                                                     \
        for (int j = 0; j < 4; ++j) {                                         \
            int g = j * 256 + tid; int row = g >> 2;                          \
            int ch = (g & 3) ^ SIG(row);                                      \
            async_copy16(A + (size_t)(m0 + row) * K_ + (kt) * BK + ch * 8,    \
                         &lds[(d) * BUFE + (j * 256 + wid * 64) * 8]);        \
        }                                                                     \
    } while (0)
#define STAGE_B(d, kt)                                                        \
    do {                                                                      \
        _Pragma("unroll")                                                     \
        for (int j = 0; j < 2; ++j) {                                         \
            int g = j * 256 + tid; int row = g >> 2;                          \
            int ch = (g & 3) ^ SIG(row);                                      \
            async_copy16(Bt + (size_t)(n0 + row) * K_ + (kt) * BK + ch * 8,   \
                         &lds[(d) * BUFE + 8192 + (j * 256 + wid * 64) * 8]); \
        }                                                                     \
    } while (0)

    STAGE_A(0, 0); STAGE_B(0, 0);
    STAGE_A(1, 1); STAGE_B(1, 1);

    const int chx = (((lane >> 4) ^ ((lane >> 1) & 3))) * 8;
    int cur = 0;
    for (int kt = 0; kt < NKT; ++kt) {
        __builtin_amdgcn_sched_barrier(0);
        if (kt < NKT - 1) asm volatile("s_waitcnt vmcnt(6)" ::: "memory");
        else              asm volatile("s_waitcnt vmcnt(0)" ::: "memory");
        __builtin_amdgcn_s_barrier();           // S_kt landed; buf(kt-1) reads done
        __builtin_amdgcn_sched_barrier(0);
        const __bf16* bufA = &lds[cur * BUFE];
        const __bf16* bufB = bufA + 8192;
        int nxt = cur + 2; if (nxt >= 3) nxt -= 3;
        bf16x8 fa[4], fb[8];
        // ---- sub-phase 1: fa + fb0..1 reads, A-stage, 8 MFMA
#pragma unroll
        for (int mf = 0; mf < 4; ++mf)
            fa[mf] = *(const bf16x8*)(&bufA[(wid * 64 + mf * 16 + (lane & 15)) * BK + chx]);
#pragma unroll
        for (int nf = 0; nf < 2; ++nf)
            fb[nf] = *(const bf16x8*)(&bufB[(nf * 16 + (lane & 15)) * BK + chx]);
        if (kt < NKT - 2) STAGE_A(nxt, kt + 2);
        __builtin_amdgcn_s_setprio(1);
#pragma unroll
        for (int mf = 0; mf < 4; ++mf)
#pragma unroll
            for (int nf = 0; nf < 2; ++nf)
                acc[mf][nf] = __builtin_amdgcn_mfma_f32_16x16x32_bf16(
                    fa[mf], fb[nf], acc[mf][nf], 0, 0, 0);
        __builtin_amdgcn_s_setprio(0);
        __builtin_amdgcn_sched_barrier(0);      // keep sub-phase 2 below
        // ---- sub-phase 2: fb2..7 reads, B-stage, 24 MFMA
#pragma unroll
        for (int nf = 2; nf < 8; ++nf)
            fb[nf] = *(const bf16x8*)(&bufB[(nf * 16 + (lane & 15)) * BK + chx]);
        if (kt < NKT - 2) STAGE_B(nxt, kt + 2);
        __builtin_amdgcn_s_setprio(1);
#pragma unroll
        for (int mf = 0; mf < 4; ++mf)
#pragma unroll
            for (int nf = 2; nf < 8; ++nf)
                acc[mf][nf] = __builtin_amdgcn_mfma_f32_16x16x32_bf16(
                    fa[mf], fb[nf], acc[mf][nf], 0, 0, 0);
        __builtin_amdgcn_s_setprio(0);
        cur += 1; if (cur >= 3) cur -= 3;
    }
#undef STAGE_A
#undef STAGE_B

    __builtin_amdgcn_s_barrier();   // main loop fully done before LDS reuse

    // epilogue: bias + exp + psum; stage wave's 64x128 E tile in LDS (stride 136)
    const int rbase = m0 + wid * 64;
    float psum[4][4] = {};
    ushort* Els = (ushort*)lds + wid * 64 * 136;
#pragma unroll
    for (int nf = 0; nf < 8; ++nf) {
        int gcol = n0 + nf * 16 + (lane & 15);
        bool live = (gcol < V_) && (gcol != PAD_IDX_);
        float bb = (gcol < V_) ? bias[gcol] : 0.f;
#pragma unroll
        for (int mf = 0; mf < 4; ++mf) {
#pragma unroll
            for (int r = 0; r < 4; ++r) {
                float e = live ? __expf(acc[mf][nf][r] + bb) : 0.f;
                psum[mf][r] += e;
                if (E16) {
                    __bf16 h = (__bf16)e;
                    Els[(mf * 16 + (lane >> 4) * 4 + r) * 136 + nf * 16 + (lane & 15)]
                        = *(const ushort*)&h;
                } else {
                    int grow = rbase + mf * 16 + (lane >> 4) * 4 + r;
                    if (gcol < V_) out[(size_t)grow * NC_ + gcol] = e;
                }
            }
        }
    }
    if (E16) {
        // 16 passes: 4 rows x 256B coalesced segments per pass
#pragma unroll
        for (int p = 0; p < 16; ++p) {
            int row_l = p * 4 + (lane >> 4);
            int g = lane & 15;
            bf16x8 v = *(const bf16x8*)(&Els[row_l * 136 + g * 8]);
            __builtin_nontemporal_store(
                v, (bf16x8*)&E[(size_t)(rbase + row_l) * VP_ + n0 + g * 8]);
        }
    }
#pragma unroll
    for (int off = 1; off < 16; off <<= 1)
#pragma unroll
        for (int mf = 0; mf < 4; ++mf)
#pragma unroll
            for (int r = 0; r < 4; ++r)
                psum[mf][r] += __shfl_xor(psum[mf][r], off);
    if ((lane & 15) == 0) {
#pragma unroll
        for (int mf = 0; mf < 4; ++mf)
#pragma unroll
            for (int r = 0; r < 4; ++r) {
                int grow = rbase + mf * 16 + (lane >> 4) * 4 + r;
                part[(size_t)grow * PSTRIDE + nb] = psum[mf][r];
            }
    }
}

// ---------------------------------------------------------------------------
// finish: rowsum from partials; out[n,0:V] = E*(1-c)/rowsum; out[n,V:] = copy
// 4 blocks per row (V quarter-split); copy part in quarter 3.
template<bool E16>
__global__ __launch_bounds__(256)
void k_finish(const ushort* __restrict__ E, const float* __restrict__ part,
              const float* __restrict__ cvec, const float* __restrict__ attn,
              const int* __restrict__ ids, float* __restrict__ out)
{
    int n = blockIdx.y;
    int q = blockIdx.x;
    int tid = threadIdx.x;
    float c = cvec[n];
    float* row = out + (size_t)n * NC_;

    __shared__ float ws4[4];
    __shared__ float cp[CV_];
    if (q == 3 && tid < CV_) cp[tid] = 0.f;

    float s = 0.f;
    for (int p = tid; p < NB_; p += 256) s += part[(size_t)n * PSTRIDE + p];
#pragma unroll
    for (int off = 32; off; off >>= 1) s += __shfl_down(s, off);
    if ((tid & 63) == 0) ws4[tid >> 6] = s;
    __syncthreads();
    float rowsum = ws4[0] + ws4[1] + ws4[2] + ws4[3];
    float sc = (1.f - c) / rowsum;

    if (q == 3 && tid < S_)
        atomicAdd(&cp[ids[tid * B_ + (n & (B_ - 1))]],
                  attn[(size_t)n * S_ + tid] * c);

    // V region split in units of 8 floats: 6250 total, quarters of 1564
    int i0 = q * 1564;
    int i1 = min(i0 + 1564, V_ / 8);
    if (E16) {
        const ushort* e = E + (size_t)n * VP_;
        for (int i = i0 + tid; i < i1; i += 256) {
            bf16x8 v = __builtin_nontemporal_load((const bf16x8*)(e + i * 8));
            f32x4 o0, o1;
            o0[0]=(float)v[0]*sc; o0[1]=(float)v[1]*sc; o0[2]=(float)v[2]*sc; o0[3]=(float)v[3]*sc;
            o1[0]=(float)v[4]*sc; o1[1]=(float)v[5]*sc; o1[2]=(float)v[6]*sc; o1[3]=(float)v[7]*sc;
            __builtin_nontemporal_store(o0, (f32x4*)(row + i * 8));
            __builtin_nontemporal_store(o1, (f32x4*)(row + i * 8 + 4));
        }
    } else {
        for (int i = i0 * 2 + tid; i < i1 * 2; i += 256) {
            f32x4 v = *(const f32x4*)(row + i * 4);
            v[0]*=sc; v[1]*=sc; v[2]*=sc; v[3]*=sc;
            *(f32x4*)(row + i * 4) = v;
        }
    }
    if (q == 3) {
        __syncthreads();
        if (tid < CV_) row[V_ + tid] = cp[tid];
    }
}

// ---------------------------------------------------------------------------
extern "C" void kernel_launch(void* const* d_in, const int* in_sizes, int n_in,
                              void* d_out, int out_size, void* d_ws, size_t ws_size,
                              hipStream_t stream)
{
    const float* hidden  = (const float*)d_in[0];
    const float* attn    = (const float*)d_in[1];
    const float* src_map = (const float*)d_in[2];
    const float* W       = (const float*)d_in[3];
    const float* bias    = (const float*)d_in[4];
    const float* w_copy  = (const float*)d_in[5];
    const float* b_copy  = (const float*)d_in[6];
    float* out = (float*)d_out;

    // workspace layout
    size_t off = 0;
    __bf16* Wt = (__bf16*)((char*)d_ws + off); off += (size_t)VP_ * K_ * 2;
    __bf16* Ab = (__bf16*)((char*)d_ws + off); off += (size_t)M_ * K_ * 2;
    float* cvec = (float*)((char*)d_ws + off); off += M_ * 4;
    int*   ids  = (int*)((char*)d_ws + off);   off += 16384;
    float* part = (float*)((char*)d_ws + off); off += (size_t)M_ * PSTRIDE * 4;
    ushort* E   = (ushort*)((char*)d_ws + off);
    bool e16 = (off + (size_t)M_ * VP_ * 2) <= ws_size;

    k_pre<<<WT_BLKS + PREP_BLKS + IDS_BLKS, 256, 0, stream>>>(
        W, Wt, hidden, w_copy, b_copy, Ab, cvec, src_map, ids);

    dim3 gg(NMT, NB_);
    dim3 gf(4, M_);
    if (e16) {
        k_gemm_exp<true><<<gg, 256, 0, stream>>>(Ab, Wt, bias, out, E, part);
        k_finish<true><<<gf, 256, 0, stream>>>(E, part, cvec, attn, ids, out);
    } else {
        k_gemm_exp<false><<<gg, 256, 0, stream>>>(Ab, Wt, bias, out, E, part);
        k_finish<false><<<gf, 256, 0, stream>>>((const ushort*)out, part, cvec, attn, ids, out);
    }
}